// Round 4
// baseline (267.337 us; speedup 1.0000x reference)
//
#include <hip/hip_runtime.h>

#define NETS 32
#define BATCH 4096
#define D0 256
#define D1 512
#define D2 512
#define D3 128
#define MT 64            // batch rows per block
#define LDA (D0 + 8)     // 264 halves -> 528 B row stride (4-bank rotation per row)
#define LDH (D1 + 8)     // 520 halves -> 1040 B row stride

using half8 = __attribute__((ext_vector_type(8))) _Float16;
using half4 = __attribute__((ext_vector_type(4))) _Float16;
using f32x4 = __attribute__((ext_vector_type(4))) float;

#define W1_N (NETS * D1 * D0)   // 4,194,304
#define W2_N (NETS * D2 * D1)   // 8,388,608
#define W3_N (NETS * D3 * D2)   // 2,097,152

// ---------------- fp32 -> fp16 cast + fragment swizzle ----------------
// Swizzled layout: fragment f = ((net*4 + w)*NF + kk*NI + ni), 512 halves each.
// Within a fragment, lane l (l = quad*16 + lane16) owns halves [l*8, l*8+8) =
// source W[net][w*NWCH + ni*16 + lane16][kk*32 + quad*8 .. +8).
// => every wave B-load in the main kernel is one contiguous 1-KB transaction.
// Source reads are single-use -> nontemporal. Dest stores stay normal (the
// converted weights are immediately re-read by mlp_fused -> leave in L2).
__global__ void cvt_weights(const float* __restrict__ W1, const float* __restrict__ W2,
                            const float* __restrict__ W3,
                            _Float16* __restrict__ W1h, _Float16* __restrict__ W2h,
                            _Float16* __restrict__ W3h) {
    const int i = blockIdx.x * blockDim.x + threadIdx.x;   // one 16-B frag-slice per thread
    constexpr int T1 = W1_N / 8, T2 = W2_N / 8, T3 = W3_N / 8;
    const float* src;
    _Float16* dst;
    if (i < T1) {
        // L1: K=256, NI=8, NF=64, n-chunk 128/wave
        int u = i, l = u & 63, f = u >> 6;
        int kkni = f & 63, netw = f >> 6;
        int ni = kkni & 7, kk = kkni >> 3;
        int net = netw >> 2, w = netw & 3;
        int n = w * 128 + ni * 16 + (l & 15);
        int k = kk * 32 + (l >> 4) * 8;
        src = W1 + (size_t)net * D1 * D0 + (size_t)n * D0 + k;
        dst = W1h + (size_t)f * 512 + l * 8;
    } else if (i < T1 + T2) {
        // L2: K=512, NI=8, NF=128
        int u = i - T1, l = u & 63, f = u >> 6;
        int kkni = f & 127, netw = f >> 7;
        int ni = kkni & 7, kk = kkni >> 3;
        int net = netw >> 2, w = netw & 3;
        int n = w * 128 + ni * 16 + (l & 15);
        int k = kk * 32 + (l >> 4) * 8;
        src = W2 + (size_t)net * D2 * D1 + (size_t)n * D1 + k;
        dst = W2h + (size_t)f * 512 + l * 8;
    } else {
        // L3: K=512, NI=2, NF=32, n-chunk 32/wave
        int u = i - T1 - T2, l = u & 63, f = u >> 6;
        int kkni = f & 31, netw = f >> 5;
        int ni = kkni & 1, kk = kkni >> 1;
        int net = netw >> 2, w = netw & 3;
        int n = w * 32 + ni * 16 + (l & 15);
        int k = kk * 32 + (l >> 4) * 8;
        src = W3 + (size_t)net * D3 * D2 + (size_t)n * D2 + k;
        dst = W3h + (size_t)f * 512 + l * 8;
    }
    f32x4 v0 = __builtin_nontemporal_load(reinterpret_cast<const f32x4*>(src));
    f32x4 v1 = __builtin_nontemporal_load(reinterpret_cast<const f32x4*>(src) + 1);
    half8 o;
    o[0] = (_Float16)v0[0]; o[1] = (_Float16)v0[1]; o[2] = (_Float16)v0[2]; o[3] = (_Float16)v0[3];
    o[4] = (_Float16)v1[0]; o[5] = (_Float16)v1[1]; o[6] = (_Float16)v1[2]; o[7] = (_Float16)v1[3];
    *reinterpret_cast<half8*>(dst) = o;
}

// ---------------- software-pipelined layer, coalesced B stream ----------------
// wl points at this (net,wave)'s first fragment + l*8. Fragments are consumed
// linearly: f = kk*NI + ni. Prefetch G fragments one group ahead.
// (Register budget note: acc[4][8]=128 AGPR + ~120 VGPR = 248/256 at 2 waves/SIMD.
//  Deeper register prefetch does NOT fit — measured regression in R1.)
// Operands are SWAPPED vs the naive form: W-fragment as A-operand, activation
// as B-operand. Both operand fragments have the same lane layout for
// 16x16x32_f16; the swap transposes C so each lane's 4 acc values are
// contiguous along n (verified numerically on HW in R1):
//   acc[mi][ni][r] = H[mi*16 + lane16][ni*16 + quad*4 + r]
template<int K, int NI, int G, int MI>
__device__ __forceinline__ void layer_mfma(const _Float16* As, int lda,
                                           const _Float16* __restrict__ wl,
                                           int lane16, int quad,
                                           f32x4 (&acc)[MI][NI]) {
    constexpr int NFR = (K / 32) * NI;
    constexpr int STEPS = NFR / G;
    half8 bcur[G], bnxt[G];
    half8 a[MI];
#pragma unroll
    for (int g = 0; g < G; ++g)
        bcur[g] = *reinterpret_cast<const half8*>(wl + (size_t)g * 512);
#pragma unroll
    for (int s = 0; s < STEPS; ++s) {
        const int fb = s * G;
        if (s + 1 < STEPS) {
#pragma unroll
            for (int g = 0; g < G; ++g)
                bnxt[g] = *reinterpret_cast<const half8*>(wl + (size_t)(fb + G + g) * 512);
        }
        if (fb % NI == 0) {
            const int kk = fb / NI;
#pragma unroll
            for (int mi = 0; mi < MI; ++mi)
                a[mi] = *reinterpret_cast<const half8*>(
                    As + (mi * 16 + lane16) * lda + kk * 32 + quad * 8);
        }
#pragma unroll
        for (int g = 0; g < G; ++g) {
            const int ni = (fb + g) % NI;
#pragma unroll
            for (int mi = 0; mi < MI; ++mi)
                acc[mi][ni] = __builtin_amdgcn_mfma_f32_16x16x32_f16(
                    bcur[g], a[mi], acc[mi][ni], 0, 0, 0);
        }
        if (s + 1 < STEPS) {
#pragma unroll
            for (int g = 0; g < G; ++g) bcur[g] = bnxt[g];
        }
    }
}

// Swapped-C layout: each lane's 4 acc values are 4 consecutive n at the same m
// -> one ds_write_b64 per (mi,ni) (4x fewer LDS write instrs than scalar),
// float4 bias load.
template<int MI, int NI>
__device__ __forceinline__ void store_act(f32x4 (&acc)[MI][NI], const float* __restrict__ bias,
                                          _Float16* dst, int ldd, int n_base,
                                          int lane16, int quad) {
#pragma unroll
    for (int ni = 0; ni < NI; ++ni) {
        const int n0 = n_base + ni * 16 + quad * 4;
        const f32x4 bv = *reinterpret_cast<const f32x4*>(bias + n0);
#pragma unroll
        for (int mi = 0; mi < MI; ++mi) {
            half4 o;
            o[0] = (_Float16)fmaxf(acc[mi][ni][0] + bv[0], 0.0f);
            o[1] = (_Float16)fmaxf(acc[mi][ni][1] + bv[1], 0.0f);
            o[2] = (_Float16)fmaxf(acc[mi][ni][2] + bv[2], 0.0f);
            o[3] = (_Float16)fmaxf(acc[mi][ni][3] + bv[3], 0.0f);
            *reinterpret_cast<half4*>(&dst[(mi * 16 + lane16) * ldd + n0]) = o;
        }
    }
}

// ---------------- fused 3-layer MLP, single in-place LDS buffer ----------------
__global__ __launch_bounds__(256, 2) void mlp_fused(
    const float* __restrict__ X,
    const _Float16* __restrict__ W1h, const float* __restrict__ b1,
    const _Float16* __restrict__ W2h, const float* __restrict__ b2,
    const _Float16* __restrict__ W3h, const float* __restrict__ b3,
    float* __restrict__ out) {
    __shared__ __align__(16) _Float16 buf[MT * LDH];   // X (LDA layout) -> H1 -> H2 (LDH)

    const int tid = threadIdx.x;
    const int w = tid >> 6;
    const int l = tid & 63;
    const int lane16 = l & 15;
    const int quad = l >> 4;

    // XCD-locality: dispatch round-robins blockIdx over 8 XCDs -> 4 nets/XCD.
    // Within a dispatch round, each XCD runs ONE net (0.92 MB fp16 weights),
    // reused by all 64 row-tiles. The 67 MB output stream is the main L2
    // polluter -> it is written nontemporal with FULL-LINE vectorized stores
    // (R3 lesson: scalar nt stores caused partial-line write amplification,
    // WRITE_SIZE 68.5->78 MB; nt X loads killed X reuse -> X loads stay normal).
    const int bb = blockIdx.x;            // 0..2047
    const int xcd = bb & 7;
    const int s = bb >> 3;                // 0..255
    const int net = xcd * 4 + (s >> 6);   // 0..31
    const int mt = s & 63;                // 0..63
    const int m0 = mt * MT;

    // ---- stage X tile [MT][D0] fp32 -> fp16 into buf (LDA layout) ----
    // MT*D0/4 = 4096 float4 chunks; 256 threads x 16 iters. Normal loads:
    // X tiles are reused 4x per XCD (net-rounds) and cross-XCD via L3.
    {
        const float* xsrc = X + (size_t)m0 * D0;
#pragma unroll
        for (int it = 0; it < 16; ++it) {
            int chunk = it * 256 + tid;   // 0..4095; 64 float4 per row
            int row = chunk >> 6;
            int c4 = chunk & 63;
            f32x4 v = *reinterpret_cast<const f32x4*>(xsrc + row * D0 + c4 * 4);
            half4 o;
            o[0] = (_Float16)v[0]; o[1] = (_Float16)v[1];
            o[2] = (_Float16)v[2]; o[3] = (_Float16)v[3];
            *reinterpret_cast<half4*>(&buf[row * LDA + c4 * 4]) = o;
        }
    }
    __syncthreads();

    // ---- layer 1: H1 = relu(X @ W1^T + b1), K=256, N=512 (wave owns 128 cols) ----
    {
        f32x4 acc[4][8] = {};
        const _Float16* wl = W1h + ((size_t)(net * 4 + w) * 64) * 512 + l * 8;
        layer_mfma<D0, 8, 4, 4>(buf, LDA, wl, lane16, quad, acc);
        __syncthreads();                               // all X reads done
        store_act<4, 8>(acc, b1 + net * D1, buf, LDH, w * 128, lane16, quad);
    }
    __syncthreads();

    // ---- layer 2: H2 = relu(H1 @ W2^T + b2), K=512, N=512 ----
    {
        f32x4 acc[4][8] = {};
        const _Float16* wl = W2h + ((size_t)(net * 4 + w) * 128) * 512 + l * 8;
        layer_mfma<D1, 8, 4, 4>(buf, LDH, wl, lane16, quad, acc);
        __syncthreads();                               // all H1 reads done
        store_act<4, 8>(acc, b2 + net * D2, buf, LDH, w * 128, lane16, quad);
    }
    __syncthreads();

    // ---- layer 3: out = H2 @ W3^T + b3, K=512, N=128 (wave owns 32 cols) ----
    {
        f32x4 acc[4][2] = {};
        const _Float16* wl = W3h + ((size_t)(net * 4 + w) * 32) * 512 + l * 8;
        layer_mfma<D2, 2, 2, 4>(buf, LDH, wl, lane16, quad, acc);
        const int n_base = w * 32;
#pragma unroll
        for (int ni = 0; ni < 2; ++ni) {
            const int n0 = n_base + ni * 16 + quad * 4;
            const f32x4 bv = *reinterpret_cast<const f32x4*>(b3 + net * D3 + n0);
#pragma unroll
            for (int mi = 0; mi < 4; ++mi) {
                const int row = m0 + mi * 16 + lane16;
                f32x4 v = acc[mi][ni] + bv;
                // full-line streaming store: the 4 quads of this instruction
                // cover a complete 64-B segment of 16 consecutive rows ->
                // safe to bypass L2 allocation (no partial-line flush).
                __builtin_nontemporal_store(v, reinterpret_cast<f32x4*>(
                    &out[(size_t)row * (NETS * D3) + net * D3 + n0]));
            }
        }
    }
}

extern "C" void kernel_launch(void* const* d_in, const int* in_sizes, int n_in,
                              void* d_out, int out_size, void* d_ws, size_t ws_size,
                              hipStream_t stream) {
    const float* x  = (const float*)d_in[0];
    const float* W1 = (const float*)d_in[1];
    const float* b1 = (const float*)d_in[2];
    const float* W2 = (const float*)d_in[3];
    const float* b2 = (const float*)d_in[4];
    const float* W3 = (const float*)d_in[5];
    const float* b3 = (const float*)d_in[6];
    float* out = (float*)d_out;

    // ws layout (fp16, swizzled): W1h | W2h | W3h  = ~29.4 MB total
    _Float16* W1h = (_Float16*)d_ws;
    _Float16* W2h = W1h + (size_t)W1_N;
    _Float16* W3h = W2h + (size_t)W2_N;

    const int totalT = (W1_N + W2_N + W3_N) / 8;       // 1,835,008 threads
    cvt_weights<<<totalT / 256, 256, 0, stream>>>(W1, W2, W3, W1h, W2h, W3h);

    mlp_fused<<<NETS * (BATCH / MT), 256, 0, stream>>>(x, W1h, b1, W2h, b2, W3h, b3, out);
}

// Round 5
// 256.410 us; speedup vs baseline: 1.0426x; 1.0426x over previous
//
#include <hip/hip_runtime.h>

#define NETS 32
#define BATCH 4096
#define D0 256
#define D1 512
#define D2 512
#define D3 128
#define MT 64            // batch rows per block
#define LDA (D0 + 8)     // 264 halves -> 528 B row stride (4-bank rotation per row)
#define LDH (D1 + 8)     // 520 halves -> 1040 B row stride

using half8 = __attribute__((ext_vector_type(8))) _Float16;
using half4 = __attribute__((ext_vector_type(4))) _Float16;
using f32x4 = __attribute__((ext_vector_type(4))) float;

#define W1_N (NETS * D1 * D0)   // 4,194,304
#define W2_N (NETS * D2 * D1)   // 8,388,608
#define W3_N (NETS * D3 * D2)   // 2,097,152

// ---------------- fp32 -> fp16 cast + fragment swizzle ----------------
// Swizzled layout: fragment f = ((net*4 + w)*NF + kk*NI + ni), 512 halves each.
// Within a fragment, lane l (l = quad*16 + lane16) owns halves [l*8, l*8+8) =
// source W[net][w*NWCH + ni*16 + lane16][kk*32 + quad*8 .. +8).
// => every wave B-load in the main kernel is one contiguous 1-KB transaction.
__global__ void cvt_weights(const float* __restrict__ W1, const float* __restrict__ W2,
                            const float* __restrict__ W3,
                            _Float16* __restrict__ W1h, _Float16* __restrict__ W2h,
                            _Float16* __restrict__ W3h) {
    const int i = blockIdx.x * blockDim.x + threadIdx.x;   // one 16-B frag-slice per thread
    constexpr int T1 = W1_N / 8, T2 = W2_N / 8, T3 = W3_N / 8;
    const float* src;
    _Float16* dst;
    if (i < T1) {
        // L1: K=256, NI=8, NF=64, n-chunk 128/wave
        int u = i, l = u & 63, f = u >> 6;
        int kkni = f & 63, netw = f >> 6;
        int ni = kkni & 7, kk = kkni >> 3;
        int net = netw >> 2, w = netw & 3;
        int n = w * 128 + ni * 16 + (l & 15);
        int k = kk * 32 + (l >> 4) * 8;
        src = W1 + (size_t)net * D1 * D0 + (size_t)n * D0 + k;
        dst = W1h + (size_t)f * 512 + l * 8;
    } else if (i < T1 + T2) {
        // L2: K=512, NI=8, NF=128
        int u = i - T1, l = u & 63, f = u >> 6;
        int kkni = f & 127, netw = f >> 7;
        int ni = kkni & 7, kk = kkni >> 3;
        int net = netw >> 2, w = netw & 3;
        int n = w * 128 + ni * 16 + (l & 15);
        int k = kk * 32 + (l >> 4) * 8;
        src = W2 + (size_t)net * D2 * D1 + (size_t)n * D1 + k;
        dst = W2h + (size_t)f * 512 + l * 8;
    } else {
        // L3: K=512, NI=2, NF=32, n-chunk 32/wave
        int u = i - T1 - T2, l = u & 63, f = u >> 6;
        int kkni = f & 31, netw = f >> 5;
        int ni = kkni & 1, kk = kkni >> 1;
        int net = netw >> 2, w = netw & 3;
        int n = w * 32 + ni * 16 + (l & 15);
        int k = kk * 32 + (l >> 4) * 8;
        src = W3 + (size_t)net * D3 * D2 + (size_t)n * D2 + k;
        dst = W3h + (size_t)f * 512 + l * 8;
    }
    float4 v0 = *reinterpret_cast<const float4*>(src);
    float4 v1 = *reinterpret_cast<const float4*>(src + 4);
    half8 o;
    o[0] = (_Float16)v0.x; o[1] = (_Float16)v0.y; o[2] = (_Float16)v0.z; o[3] = (_Float16)v0.w;
    o[4] = (_Float16)v1.x; o[5] = (_Float16)v1.y; o[6] = (_Float16)v1.z; o[7] = (_Float16)v1.w;
    *reinterpret_cast<half8*>(dst) = o;
}

// ---------------- software-pipelined layer, coalesced B stream ----------------
// wl points at this (net,wave)'s first fragment + l*8. Fragments are consumed
// linearly: f = kk*NI + ni. B: prefetch G fragments one group ahead (compiler
// emits counted-vmcnt pipeline; 1-step distance covers L2 latency).
// A: 3-slot ds_read ring — kk+2's fragments issue when entering kk (2-step
// ~600 cy cover), removing the same-step lgkmcnt stall at every kk boundary.
// All ring indices are compile-time after full unroll.
template<int K, int NI, int G, int MI>
__device__ __forceinline__ void layer_mfma(const _Float16* As, int lda,
                                           const _Float16* __restrict__ wl,
                                           int lane16, int quad,
                                           f32x4 (&acc)[MI][NI]) {
    constexpr int KK = K / 32;
    constexpr int NFR = KK * NI;
    constexpr int STEPS = NFR / G;
    half8 bcur[G], bnxt[G];
    half8 a[3][MI];
#pragma unroll
    for (int g = 0; g < G; ++g)
        bcur[g] = *reinterpret_cast<const half8*>(wl + (size_t)g * 512);
#pragma unroll
    for (int j = 0; j < 2 && j < KK; ++j)
#pragma unroll
        for (int mi = 0; mi < MI; ++mi)
            a[j][mi] = *reinterpret_cast<const half8*>(
                As + (mi * 16 + lane16) * lda + j * 32 + quad * 8);
#pragma unroll
    for (int s = 0; s < STEPS; ++s) {
        const int fb = s * G;
        const int kk = fb / NI;
        if (s + 1 < STEPS) {
#pragma unroll
            for (int g = 0; g < G; ++g)
                bnxt[g] = *reinterpret_cast<const half8*>(wl + (size_t)(fb + G + g) * 512);
        }
        if (fb % NI == 0) {
            const int pk = kk + 2;
            if (pk < KK) {
#pragma unroll
                for (int mi = 0; mi < MI; ++mi)
                    a[pk % 3][mi] = *reinterpret_cast<const half8*>(
                        As + (mi * 16 + lane16) * lda + pk * 32 + quad * 8);
            }
        }
#pragma unroll
        for (int g = 0; g < G; ++g) {
            const int ni = (fb + g) % NI;
#pragma unroll
            for (int mi = 0; mi < MI; ++mi)
                acc[mi][ni] = __builtin_amdgcn_mfma_f32_16x16x32_f16(
                    a[kk % 3][mi], bcur[g], acc[mi][ni], 0, 0, 0);
        }
        if (s + 1 < STEPS) {
#pragma unroll
            for (int g = 0; g < G; ++g) bcur[g] = bnxt[g];
        }
    }
}

template<int MI, int NI>
__device__ __forceinline__ void store_act(f32x4 (&acc)[MI][NI], const float* __restrict__ bias,
                                          _Float16* dst, int ldd, int n_base,
                                          int lane16, int quad) {
#pragma unroll
    for (int ni = 0; ni < NI; ++ni) {
        float bv = bias[n_base + ni * 16 + lane16];
        int col = n_base + ni * 16 + lane16;
#pragma unroll
        for (int mi = 0; mi < MI; ++mi) {
#pragma unroll
            for (int r = 0; r < 4; ++r) {
                float v = acc[mi][ni][r] + bv;
                v = fmaxf(v, 0.0f);                        // relu
                int row = mi * 16 + quad * 4 + r;
                dst[row * ldd + col] = (_Float16)v;
            }
        }
    }
}

// ---------------- fused 3-layer MLP, single in-place LDS buffer ----------------
__global__ __launch_bounds__(256, 2) void mlp_fused(
    const float* __restrict__ X,
    const _Float16* __restrict__ W1h, const float* __restrict__ b1,
    const _Float16* __restrict__ W2h, const float* __restrict__ b2,
    const _Float16* __restrict__ W3h, const float* __restrict__ b3,
    float* __restrict__ out) {
    __shared__ __align__(16) _Float16 buf[MT * LDH];   // X (LDA layout) -> H1 -> H2 (LDH)

    const int tid = threadIdx.x;
    const int w = tid >> 6;
    const int l = tid & 63;
    const int lane16 = l & 15;
    const int quad = l >> 4;

    // XCD-locality: dispatch round-robins blockIdx over 8 XCDs -> 4 nets/XCD
    // (3.7 MB fp16 weights per XCD-L2).
    const int bb = blockIdx.x;            // 0..2047
    const int xcd = bb & 7;
    const int s = bb >> 3;                // 0..255
    const int net = xcd * 4 + (s >> 6);   // 0..31
    const int mt = s & 63;                // 0..63
    const int m0 = mt * MT;

    // ---- stage X tile [MT][D0] fp32 -> fp16 into buf (LDA layout) ----
    // MT*D0/4 = 4096 float4 chunks; 256 threads x 16 iters.
    {
        const float* xsrc = X + (size_t)m0 * D0;
#pragma unroll
        for (int it = 0; it < 16; ++it) {
            int chunk = it * 256 + tid;   // 0..4095; 64 float4 per row
            int row = chunk >> 6;
            int c4 = chunk & 63;
            float4 v = *reinterpret_cast<const float4*>(xsrc + row * D0 + c4 * 4);
            half4 o;
            o[0] = (_Float16)v.x; o[1] = (_Float16)v.y;
            o[2] = (_Float16)v.z; o[3] = (_Float16)v.w;
            *reinterpret_cast<half4*>(&buf[row * LDA + c4 * 4]) = o;
        }
    }
    __syncthreads();

    // ---- layer 1: H1 = relu(X @ W1^T + b1), K=256, N=512 (wave owns 128 cols) ----
    {
        f32x4 acc[4][8] = {};
        const _Float16* wl = W1h + ((size_t)(net * 4 + w) * 64) * 512 + l * 8;
        layer_mfma<D0, 8, 4, 4>(buf, LDA, wl, lane16, quad, acc);
        __syncthreads();                               // all X reads done
        store_act<4, 8>(acc, b1 + net * D1, buf, LDH, w * 128, lane16, quad);
    }
    __syncthreads();

    // ---- layer 2: H2 = relu(H1 @ W2^T + b2), K=512, N=512 ----
    {
        f32x4 acc[4][8] = {};
        const _Float16* wl = W2h + ((size_t)(net * 4 + w) * 128) * 512 + l * 8;
        layer_mfma<D1, 8, 4, 4>(buf, LDH, wl, lane16, quad, acc);
        __syncthreads();                               // all H1 reads done
        store_act<4, 8>(acc, b2 + net * D2, buf, LDH, w * 128, lane16, quad);
    }
    __syncthreads();

    // ---- layer 3: out = H2 @ W3^T + b3, K=512, N=128 (wave owns 32 cols) ----
    {
        f32x4 acc[4][2] = {};
        const _Float16* wl = W3h + ((size_t)(net * 4 + w) * 32) * 512 + l * 8;
        layer_mfma<D2, 2, 2, 4>(buf, LDH, wl, lane16, quad, acc);
        const int n_base = w * 32;
#pragma unroll
        for (int ni = 0; ni < 2; ++ni) {
            float bv = b3[net * D3 + n_base + ni * 16 + lane16];
            int col = net * D3 + n_base + ni * 16 + lane16;
#pragma unroll
            for (int mi = 0; mi < 4; ++mi) {
#pragma unroll
                for (int r = 0; r < 4; ++r) {
                    int row = m0 + mi * 16 + quad * 4 + r;
                    out[(size_t)row * (NETS * D3) + col] = acc[mi][ni][r] + bv;
                }
            }
        }
    }
}

extern "C" void kernel_launch(void* const* d_in, const int* in_sizes, int n_in,
                              void* d_out, int out_size, void* d_ws, size_t ws_size,
                              hipStream_t stream) {
    const float* x  = (const float*)d_in[0];
    const float* W1 = (const float*)d_in[1];
    const float* b1 = (const float*)d_in[2];
    const float* W2 = (const float*)d_in[3];
    const float* b2 = (const float*)d_in[4];
    const float* W3 = (const float*)d_in[5];
    const float* b3 = (const float*)d_in[6];
    float* out = (float*)d_out;

    // ws layout (fp16, swizzled): W1h | W2h | W3h  = ~29.4 MB total
    _Float16* W1h = (_Float16*)d_ws;
    _Float16* W2h = W1h + (size_t)W1_N;
    _Float16* W3h = W2h + (size_t)W2_N;

    const int totalT = (W1_N + W2_N + W3_N) / 8;       // 1,835,008 threads
    cvt_weights<<<totalT / 256, 256, 0, stream>>>(W1, W2, W3, W1h, W2h, W3h);

    mlp_fused<<<NETS * (BATCH / MT), 256, 0, stream>>>(x, W1h, b1, W2h, b2, W3h, b3, out);
}

// Round 6
// 247.436 us; speedup vs baseline: 1.0804x; 1.0363x over previous
//
#include <hip/hip_runtime.h>

#define NETS 32
#define BATCH 4096
#define D0 256
#define D1 512
#define D2 512
#define D3 128
#define MT 64            // batch rows per block
#define LDA (D0 + 8)     // 264 halves -> 528 B row stride
#define LDH (D1 + 8)     // 520 halves -> 1040 B row stride

using half8 = __attribute__((ext_vector_type(8))) _Float16;
using half4 = __attribute__((ext_vector_type(4))) _Float16;
using f32x4 = __attribute__((ext_vector_type(4))) float;

#define W1_N (NETS * D1 * D0)   // 4,194,304
#define W2_N (NETS * D2 * D1)   // 8,388,608
#define W3_N (NETS * D3 * D2)   // 2,097,152

// ---------------- fp32 -> fp16 cast + fragment swizzle ----------------
// 8-wave layout: fragment f = ((net*8 + w)*NF + kk*NI + ni), 512 halves each.
// Fragment slot l' (l' = quad*16 + lane16) owns halves [l'*8, l'*8+8) =
// W[net][n_base + ni*16 + (l'&15)][kk*32 + (l'>>4)*8 .. +8).
// COALESCED READ (R5 fix): lane l reads row (l>>2), k-chunk (l&3)*8 -> each
// row's 4 lanes cover 128 contiguous bytes (full sectors; old scheme used
// 32 B per scattered row -> ~4x read amplification, cvt was ~100 us).
// The layout permutation moves to the store: slot l' = ((l&3)<<4) | (l>>2);
// the wave still writes one full contiguous 1-KB block (coalesced by addr).
__global__ void cvt_weights(const float* __restrict__ W1, const float* __restrict__ W2,
                            const float* __restrict__ W3,
                            _Float16* __restrict__ W1h, _Float16* __restrict__ W2h,
                            _Float16* __restrict__ W3h) {
    const int i = blockIdx.x * blockDim.x + threadIdx.x;   // one 16-B frag-slice per thread
    constexpr int T1 = W1_N / 8, T2 = W2_N / 8, T3 = W3_N / 8;
    const float* src;
    _Float16* dstf;
    int l;
    if (i < T1) {
        // L1: K=256, KK=8, NI=4, NF=32, 64 cols/wave
        int u = i; l = u & 63; int f = u >> 6;
        int ni = f & 3, kk = (f >> 2) & 7;
        int netw = f >> 5;                 // net*8 + w
        int w = netw & 7, net = netw >> 3;
        int n = w * 64 + ni * 16 + (l >> 2);
        int k = kk * 32 + (l & 3) * 8;
        src = W1 + (size_t)net * D1 * D0 + (size_t)n * D0 + k;
        dstf = W1h + (size_t)f * 512;
    } else if (i < T1 + T2) {
        // L2: K=512, KK=16, NI=4, NF=64
        int u = i - T1; l = u & 63; int f = u >> 6;
        int ni = f & 3, kk = (f >> 2) & 15;
        int netw = f >> 6;
        int w = netw & 7, net = netw >> 3;
        int n = w * 64 + ni * 16 + (l >> 2);
        int k = kk * 32 + (l & 3) * 8;
        src = W2 + (size_t)net * D2 * D1 + (size_t)n * D1 + k;
        dstf = W2h + (size_t)f * 512;
    } else {
        // L3: K=512, KK=16, NI=1, NF=16, 16 cols/wave
        int u = i - T1 - T2; l = u & 63; int f = u >> 6;
        int kk = f & 15;
        int netw = f >> 4;
        int w = netw & 7, net = netw >> 3;
        int n = w * 16 + (l >> 2);
        int k = kk * 32 + (l & 3) * 8;
        src = W3 + (size_t)net * D3 * D2 + (size_t)n * D2 + k;
        dstf = W3h + (size_t)f * 512;
    }
    float4 v0 = *reinterpret_cast<const float4*>(src);
    float4 v1 = *reinterpret_cast<const float4*>(src + 4);
    half8 o;
    o[0] = (_Float16)v0.x; o[1] = (_Float16)v0.y; o[2] = (_Float16)v0.z; o[3] = (_Float16)v0.w;
    o[4] = (_Float16)v1.x; o[5] = (_Float16)v1.y; o[6] = (_Float16)v1.z; o[7] = (_Float16)v1.w;
    const int lp = ((l & 3) << 4) | (l >> 2);          // slot permutation
    *reinterpret_cast<half8*>(dstf + lp * 8) = o;
}

// ---------------- software-pipelined layer, coalesced B stream ----------------
// R0 structure exactly (single-slot A, G-group B double-buffer): per-wave
// pipelining deeper than this spills (R1/R5 measured). Latency hiding now
// comes from 4 waves/SIMD TLP instead.
template<int K, int NI, int G, int MI>
__device__ __forceinline__ void layer_mfma(const _Float16* As, int lda,
                                           const _Float16* __restrict__ wl,
                                           int lane16, int quad,
                                           f32x4 (&acc)[MI][NI]) {
    constexpr int NFR = (K / 32) * NI;
    constexpr int STEPS = NFR / G;
    half8 bcur[G], bnxt[G];
    half8 a[MI];
#pragma unroll
    for (int g = 0; g < G; ++g)
        bcur[g] = *reinterpret_cast<const half8*>(wl + (size_t)g * 512);
#pragma unroll
    for (int s = 0; s < STEPS; ++s) {
        const int fb = s * G;
        if (s + 1 < STEPS) {
#pragma unroll
            for (int g = 0; g < G; ++g)
                bnxt[g] = *reinterpret_cast<const half8*>(wl + (size_t)(fb + G + g) * 512);
        }
        if (fb % NI == 0) {
            const int kk = fb / NI;
#pragma unroll
            for (int mi = 0; mi < MI; ++mi)
                a[mi] = *reinterpret_cast<const half8*>(
                    As + (mi * 16 + lane16) * lda + kk * 32 + quad * 8);
        }
#pragma unroll
        for (int g = 0; g < G; ++g) {
            const int ni = (fb + g) % NI;
#pragma unroll
            for (int mi = 0; mi < MI; ++mi)
                acc[mi][ni] = __builtin_amdgcn_mfma_f32_16x16x32_f16(a[mi], bcur[g], acc[mi][ni], 0, 0, 0);
        }
        if (s + 1 < STEPS) {
#pragma unroll
            for (int g = 0; g < G; ++g) bcur[g] = bnxt[g];
        }
    }
}

template<int MI, int NI>
__device__ __forceinline__ void store_act(f32x4 (&acc)[MI][NI], const float* __restrict__ bias,
                                          _Float16* dst, int ldd, int n_base,
                                          int lane16, int quad) {
#pragma unroll
    for (int ni = 0; ni < NI; ++ni) {
        float bv = bias[n_base + ni * 16 + lane16];
        int col = n_base + ni * 16 + lane16;
#pragma unroll
        for (int mi = 0; mi < MI; ++mi) {
#pragma unroll
            for (int r = 0; r < 4; ++r) {
                float v = acc[mi][ni][r] + bv;
                v = fmaxf(v, 0.0f);                        // relu
                int row = mi * 16 + quad * 4 + r;
                dst[row * ldd + col] = (_Float16)v;
            }
        }
    }
}

// ---------------- fused 3-layer MLP, 8 waves/block, 4 waves/SIMD ----------------
// Same 64-row x full-N tile and 65-KB LDS as R0, but 512 threads: wave owns
// 64x64 (acc[4][4]=64 VGPRs) -> fits the 128-reg cap of 4 waves/SIMD.
// 2 blocks/CU (LDS-limited) x 8 waves = 16 waves/CU: doubled TLP covers the
// B-stream vmcnt and A-frag lgkmcnt stalls that per-wave pipelining couldn't.
__global__ __launch_bounds__(512, 4) void mlp_fused(
    const float* __restrict__ X,
    const _Float16* __restrict__ W1h, const float* __restrict__ b1,
    const _Float16* __restrict__ W2h, const float* __restrict__ b2,
    const _Float16* __restrict__ W3h, const float* __restrict__ b3,
    float* __restrict__ out) {
    __shared__ __align__(16) _Float16 buf[MT * LDH];   // X (LDA layout) -> H1 -> H2 (LDH)

    const int tid = threadIdx.x;
    const int w = tid >> 6;               // 0..7
    const int l = tid & 63;
    const int lane16 = l & 15;
    const int quad = l >> 4;

    // XCD-locality: dispatch round-robins blockIdx over 8 XCDs -> 4 nets/XCD.
    const int bb = blockIdx.x;            // 0..2047
    const int xcd = bb & 7;
    const int s = bb >> 3;                // 0..255
    const int net = xcd * 4 + (s >> 6);   // 0..31
    const int mt = s & 63;                // 0..63
    const int m0 = mt * MT;

    // ---- stage X tile [MT][D0] fp32 -> fp16 into buf (LDA layout) ----
    // MT*D0/4 = 4096 float4 chunks; 512 threads x 8 iters.
    {
        const float* xsrc = X + (size_t)m0 * D0;
#pragma unroll
        for (int it = 0; it < 8; ++it) {
            int chunk = it * 512 + tid;   // 0..4095; 64 float4 per row
            int row = chunk >> 6;
            int c4 = chunk & 63;
            float4 v = *reinterpret_cast<const float4*>(xsrc + row * D0 + c4 * 4);
            half4 o;
            o[0] = (_Float16)v.x; o[1] = (_Float16)v.y;
            o[2] = (_Float16)v.z; o[3] = (_Float16)v.w;
            *reinterpret_cast<half4*>(&buf[row * LDA + c4 * 4]) = o;
        }
    }
    __syncthreads();

    // ---- layer 1: H1 = relu(X @ W1^T + b1), K=256, N=512 (wave owns 64 cols) ----
    {
        f32x4 acc[4][4] = {};
        const _Float16* wl = W1h + ((size_t)(net * 8 + w) * 32) * 512 + l * 8;
        layer_mfma<D0, 4, 2, 4>(buf, LDA, wl, lane16, quad, acc);
        __syncthreads();                               // all X reads done
        store_act<4, 4>(acc, b1 + net * D1, buf, LDH, w * 64, lane16, quad);
    }
    __syncthreads();

    // ---- layer 2: H2 = relu(H1 @ W2^T + b2), K=512, N=512 ----
    {
        f32x4 acc[4][4] = {};
        const _Float16* wl = W2h + ((size_t)(net * 8 + w) * 64) * 512 + l * 8;
        layer_mfma<D1, 4, 2, 4>(buf, LDH, wl, lane16, quad, acc);
        __syncthreads();                               // all H1 reads done
        store_act<4, 4>(acc, b2 + net * D2, buf, LDH, w * 64, lane16, quad);
    }
    __syncthreads();

    // ---- layer 3: out = H2 @ W3^T + b3, K=512, N=128 (wave owns 16 cols) ----
    {
        f32x4 acc[4][1] = {};
        const _Float16* wl = W3h + ((size_t)(net * 8 + w) * 16) * 512 + l * 8;
        layer_mfma<D2, 1, 1, 4>(buf, LDH, wl, lane16, quad, acc);
        const int n_base = w * 16;
        float bv = b3[net * D3 + n_base + lane16];
        int col = net * D3 + n_base + lane16;
#pragma unroll
        for (int mi = 0; mi < 4; ++mi) {
#pragma unroll
            for (int r = 0; r < 4; ++r) {
                int row = m0 + mi * 16 + quad * 4 + r;
                out[(size_t)row * (NETS * D3) + col] = acc[mi][0][r] + bv;
            }
        }
    }
}

extern "C" void kernel_launch(void* const* d_in, const int* in_sizes, int n_in,
                              void* d_out, int out_size, void* d_ws, size_t ws_size,
                              hipStream_t stream) {
    const float* x  = (const float*)d_in[0];
    const float* W1 = (const float*)d_in[1];
    const float* b1 = (const float*)d_in[2];
    const float* W2 = (const float*)d_in[3];
    const float* b2 = (const float*)d_in[4];
    const float* W3 = (const float*)d_in[5];
    const float* b3 = (const float*)d_in[6];
    float* out = (float*)d_out;

    // ws layout (fp16, swizzled): W1h | W2h | W3h  = ~29.4 MB total
    _Float16* W1h = (_Float16*)d_ws;
    _Float16* W2h = W1h + (size_t)W1_N;
    _Float16* W3h = W2h + (size_t)W2_N;

    const int totalT = (W1_N + W2_N + W3_N) / 8;       // 1,835,008 threads
    cvt_weights<<<totalT / 256, 256, 0, stream>>>(W1, W2, W3, W1h, W2h, W3h);

    mlp_fused<<<NETS * (BATCH / MT), 512, 0, stream>>>(x, W1h, b1, W2h, b2, W3h, b3, out);
}